// Round 14
// baseline (272.351 us; speedup 1.0000x reference)
//
#include <hip/hip_runtime.h>

// ---------------------------------------------------------------------------
// FlaxAttention: x@Wqkv -> LN(q),LN(k) -> causal flash attn -> ctx@out_W
// B=2 S=2048 D=2048 H=16 Dh=128. All matmuls bf16 MFMA (fp32 accum).
// ---------------------------------------------------------------------------

typedef float f32x4 __attribute__((ext_vector_type(4)));
typedef short s16x8 __attribute__((ext_vector_type(8)));
typedef short s16x4 __attribute__((ext_vector_type(4)));

static __device__ __forceinline__ unsigned short f2bf(float f) {
  unsigned u = __builtin_bit_cast(unsigned, f);
  unsigned r = u + 0x7fffu + ((u >> 16) & 1u);   // RNE
  return (unsigned short)(r >> 16);
}
static __device__ __forceinline__ float bf2f(unsigned short s) {
  unsigned u = ((unsigned)s) << 16;
  return __builtin_bit_cast(float, u);
}

static __device__ __forceinline__ void gload_lds16(const unsigned short* g, unsigned short* l) {
  __builtin_amdgcn_global_load_lds((const __attribute__((address_space(1))) void*)g,
                                   (__attribute__((address_space(3))) void*)l, 16, 0, 0);
}

// -------- fused preprocessing: x->bf16, Wqkv^T->bf16, outW^T->bf16 ----------
__global__ __launch_bounds__(256) void k_pre(const float4* __restrict__ x,
                                             s16x4* __restrict__ xb,
                                             const float* __restrict__ Wqkv,
                                             unsigned short* __restrict__ wT,
                                             const float* __restrict__ outW,
                                             unsigned short* __restrict__ owT) {
  __shared__ float tile[32][33];
  const int bid = blockIdx.x, t = threadIdx.x;
  if (bid < 8192) {
    int i = bid * 256 + t;
    float4 v = x[i];
    s16x4 o = { (short)f2bf(v.x), (short)f2bf(v.y), (short)f2bf(v.z), (short)f2bf(v.w) };
    xb[i] = o;
    return;
  }
  const float* in;
  unsigned short* out;
  int K = 2048, N, n0, k0;
  if (bid < 20480) {
    int b2 = bid - 8192;
    in = Wqkv; out = wT; N = 6144;
    n0 = (b2 % 192) * 32; k0 = (b2 / 192) * 32;
  } else {
    int b2 = bid - 20480;
    in = outW; out = owT; N = 2048;
    n0 = (b2 & 63) * 32; k0 = (b2 >> 6) * 32;
  }
  const int tx = t & 31, ty = t >> 5;
#pragma unroll
  for (int rr = 0; rr < 4; ++rr) {
    int kr = ty + rr * 8;
    tile[kr][tx] = in[(size_t)(k0 + kr) * N + n0 + tx];
  }
  __syncthreads();
#pragma unroll
  for (int rr = 0; rr < 4; ++rr) {
    int nr = ty + rr * 8;
    out[(size_t)(n0 + nr) * K + k0 + tx] = f2bf(tile[tx][nr]);
  }
}

// ---- 128 x (NFN*32) GEMM, BK=32, dbuf, 4 waves, 3 blocks/CU (bf16 MFMA) ----
// (unchanged from R6 -- measured best: ~111us/936TF on QKV, MfmaUtil 40%)
template <int BF16OUT, int NFN, int MINW>
__global__ __launch_bounds__(256, MINW) void k_gw(const unsigned short* __restrict__ A,
                                                  const unsigned short* __restrict__ Bt,
                                                  void* __restrict__ Cout,
                                                  int N, int K, int npx) {
  __shared__ unsigned short sA[2 * 128 * 32];            // 16KB
  __shared__ unsigned short sB[2 * NFN * 32 * 32];       // 32KB @NFN=8
  const int t = threadIdx.x;
  const int wid = t >> 6, lane = t & 63, g = lane >> 4, l15 = lane & 15;
  const int wm = wid >> 1, wn = wid & 1;

  const int xcd = (int)blockIdx.x & 7, idx = (int)blockIdx.x >> 3;
  const int m0 = (idx / npx) * 128;
  const int n0 = (xcd * npx + idx % npx) * (NFN * 32);

  const int u = (t & 7) ^ ((t >> 3) & 7);
  const int srow = 2 * (t >> 3) + (u >> 2);
  const int sk = (u & 3) * 8;
  const unsigned short* pA = A  + (size_t)(m0 + srow) * K + sk;
  const unsigned short* pB = Bt + (size_t)(n0 + srow) * K + sk;

  auto stage = [&](int kt, int buf) {
#pragma unroll
    for (int j = 0; j < 2; ++j)
      gload_lds16(pA + (size_t)(j * 64) * K + kt * 32,
                  sA + buf * 4096 + j * 2048 + t * 8);
#pragma unroll
    for (int j = 0; j < NFN / 2; ++j)
      gload_lds16(pB + (size_t)(j * 64) * K + kt * 32,
                  sB + buf * (NFN * 1024) + j * 2048 + t * 8);
  };

  const int si = (((l15 & 1) * 4 + g) ^ ((l15 >> 1) & 7));
  const int baseA = (wm * 32 + (l15 >> 1)) * 64 + si * 8;
  const int baseB = (wn * NFN * 8 + (l15 >> 1)) * 64 + si * 8;

  f32x4 acc[4][NFN];
#pragma unroll
  for (int fm = 0; fm < 4; ++fm)
#pragma unroll
    for (int fn = 0; fn < NFN; ++fn) acc[fm][fn] = (f32x4){0.f, 0.f, 0.f, 0.f};

  const int NK = K >> 5;
  stage(0, 0); stage(1, 1);
  if constexpr (NFN == 8) asm volatile("s_waitcnt vmcnt(6)" ::: "memory");
  else                    asm volatile("s_waitcnt vmcnt(4)" ::: "memory");
  __builtin_amdgcn_sched_barrier(0);
  __builtin_amdgcn_s_barrier();

  for (int s = 0; s < NK; ++s) {
    const unsigned short* aT = sA + (s & 1) * 4096;
    const unsigned short* bT = sB + (s & 1) * (NFN * 1024);

    s16x8 af[4];
#pragma unroll
    for (int fm = 0; fm < 4; ++fm) af[fm] = *(const s16x8*)&aT[baseA + fm * 512];
    __builtin_amdgcn_s_setprio(1);
#pragma unroll
    for (int fn = 0; fn < NFN; ++fn) {
      s16x8 bf = *(const s16x8*)&bT[baseB + fn * 512];
#pragma unroll
      for (int fm = 0; fm < 4; ++fm)
        acc[fm][fn] = __builtin_amdgcn_mfma_f32_16x16x32_bf16(af[fm], bf, acc[fm][fn], 0, 0, 0);
    }
    __builtin_amdgcn_s_setprio(0);

    __builtin_amdgcn_sched_barrier(0);
    __builtin_amdgcn_s_barrier();            // all reads of buf[s&1] complete
    if (s + 2 < NK) {
      stage(s + 2, s & 1);                   // refill the buffer just freed
      if constexpr (NFN == 8) asm volatile("s_waitcnt vmcnt(6)" ::: "memory");
      else                    asm volatile("s_waitcnt vmcnt(4)" ::: "memory");
    } else if (s + 1 < NK) {
      asm volatile("s_waitcnt vmcnt(0)" ::: "memory");
    }
    __builtin_amdgcn_sched_barrier(0);
    __builtin_amdgcn_s_barrier();            // tile s+1 visible to all
  }

#pragma unroll
  for (int fm = 0; fm < 4; ++fm)
#pragma unroll
    for (int fn = 0; fn < NFN; ++fn)
#pragma unroll
      for (int r = 0; r < 4; ++r) {
        const int row = m0 + wm * 64 + fm * 16 + g * 4 + r;
        const int col = n0 + wn * (NFN * 16) + fn * 16 + l15;
        if (BF16OUT)
          ((unsigned short*)Cout)[(size_t)row * N + col] = f2bf(acc[fm][fn][r]);
        else
          ((float*)Cout)[(size_t)row * N + col] = acc[fm][fn][r];
      }
}

// ---- out-projection GEMM: 128x64 tile, BK=64, dbuf, 3 blocks/CU ------------
// Session laws: >=16 MFMA/wave/iter (R12: 8 fails) AND >=3 blocks/CU (R6/R11:
// 2/CU runs ~1.4x worse per iter). k_go satisfied density but 64KB LDS capped
// it at 2/CU; this variant: LDS 48KB = 2 x (A 16K + B 8K) -> 3 co-resident.
// 4 waves 2m x 2n, wave = 64x32, acc[4][2], 16 MFMA/iter, NK=32.
// Grid = 32m x 32n = 1024 blocks (4/CU queued, 3 resident, backfilled).
// Stage = 6 gloads (A 4 + B 2); gate vmcnt(6) retires tile s+1 (same proven
// hazard structure as R6/k_go: stage targets the buffer read this iter,
// whose reads completed before the preceding barrier).
// BK=64 layout: row = 128B line; chunk c at 16B-slot (c ^ (row&7)); source
// pre-inverse-swizzled u=(t&7)^((t>>3)&7).
__global__ __launch_bounds__(256, 3) void k_go3(const unsigned short* __restrict__ A,
                                                const unsigned short* __restrict__ Bt,
                                                float* __restrict__ Cout,
                                                int N, int K, int npx) {
  __shared__ unsigned short sA[2 * 128 * 64];   // 32KB
  __shared__ unsigned short sB[2 * 64 * 64];    // 16KB
  const int t = threadIdx.x;
  const int wid = t >> 6, lane = t & 63, g = lane >> 4, l15 = lane & 15;
  const int wm = wid >> 1, wn = wid & 1;

  const int xcd = (int)blockIdx.x & 7, idx = (int)blockIdx.x >> 3;
  const int m0 = (idx / npx) * 128;
  const int n0 = (xcd * npx + idx % npx) * 64;

  const int u = (t & 7) ^ ((t >> 3) & 7);
  const unsigned short* pA = A  + (size_t)(m0 + (t >> 3)) * K + u * 8;
  const unsigned short* pB = Bt + (size_t)(n0 + (t >> 3)) * K + u * 8;

  auto stage = [&](int kt, int buf) {
#pragma unroll
    for (int j = 0; j < 4; ++j)
      gload_lds16(pA + (size_t)(j * 32) * K + kt * 64,
                  sA + buf * 8192 + j * 2048 + t * 8);
#pragma unroll
    for (int j = 0; j < 2; ++j)
      gload_lds16(pB + (size_t)(j * 32) * K + kt * 64,
                  sB + buf * 4096 + j * 2048 + t * 8);
  };

  const int x7 = l15 & 7;
  const int sl0 = (g ^ x7) * 8, sl1 = ((4 + g) ^ x7) * 8;   // ks=0,1 slots
  const int baseA = (wm * 64 + l15) * 64;   // + fm*1024 + sl
  const int baseB = (wn * 32 + l15) * 64;   // + fn*1024 + sl

  f32x4 acc[4][2];
#pragma unroll
  for (int fm = 0; fm < 4; ++fm)
#pragma unroll
    for (int fn = 0; fn < 2; ++fn) acc[fm][fn] = (f32x4){0.f, 0.f, 0.f, 0.f};

  const int NK = K >> 6;
  stage(0, 0); stage(1, 1);
  asm volatile("s_waitcnt vmcnt(6)" ::: "memory");   // tile 0's 6 landed
  __builtin_amdgcn_sched_barrier(0);
  __builtin_amdgcn_s_barrier();

  for (int s = 0; s < NK; ++s) {
    const unsigned short* aT = sA + (s & 1) * 8192;
    const unsigned short* bT = sB + (s & 1) * 4096;

    s16x8 af[4][2];
#pragma unroll
    for (int fm = 0; fm < 4; ++fm) {
      af[fm][0] = *(const s16x8*)&aT[baseA + fm * 1024 + sl0];
      af[fm][1] = *(const s16x8*)&aT[baseA + fm * 1024 + sl1];
    }
    __builtin_amdgcn_s_setprio(1);
#pragma unroll
    for (int fn = 0; fn < 2; ++fn) {
      s16x8 bf0 = *(const s16x8*)&bT[baseB + fn * 1024 + sl0];
      s16x8 bf1 = *(const s16x8*)&bT[baseB + fn * 1024 + sl1];
#pragma unroll
      for (int fm = 0; fm < 4; ++fm) {
        acc[fm][fn] = __builtin_amdgcn_mfma_f32_16x16x32_bf16(af[fm][0], bf0, acc[fm][fn], 0, 0, 0);
        acc[fm][fn] = __builtin_amdgcn_mfma_f32_16x16x32_bf16(af[fm][1], bf1, acc[fm][fn], 0, 0, 0);
      }
    }
    __builtin_amdgcn_s_setprio(0);

    __builtin_amdgcn_sched_barrier(0);
    __builtin_amdgcn_s_barrier();            // all reads of buf[s&1] complete
    if (s + 2 < NK) {
      stage(s + 2, s & 1);                   // refill the buffer just freed
      asm volatile("s_waitcnt vmcnt(6)" ::: "memory");   // tile s+1 landed
    } else if (s + 1 < NK) {
      asm volatile("s_waitcnt vmcnt(0)" ::: "memory");
    }
    __builtin_amdgcn_sched_barrier(0);
    __builtin_amdgcn_s_barrier();            // tile s+1 visible to all
  }

#pragma unroll
  for (int fm = 0; fm < 4; ++fm)
#pragma unroll
    for (int fn = 0; fn < 2; ++fn)
#pragma unroll
      for (int r = 0; r < 4; ++r) {
        const int row = m0 + wm * 64 + fm * 16 + g * 4 + r;
        const int col = n0 + wn * 32 + fn * 16 + l15;
        Cout[(size_t)row * N + col] = acc[fm][fn][r];
      }
}

// ------- fused: LayerNorm(q,k) in place + V -> v_t PV-fragment order --------
__global__ __launch_bounds__(256) void k_lnvt(unsigned short* __restrict__ qkv,
                                              const float* __restrict__ qsc,
                                              const float* __restrict__ ksc,
                                              unsigned short* __restrict__ vt) {
  __shared__ union {
    float red[8];
    unsigned short tl[64][136];
  } sm;
  const int bid = blockIdx.x, t = threadIdx.x;
  if (bid < 4096) {
    const int w = t >> 6;
    unsigned short* base = qkv + (size_t)bid * 6144;
#pragma unroll
    for (int part = 0; part < 2; ++part) {
      unsigned short* p = base + part * 2048 + t * 8;
      s16x8 v = *(const s16x8*)p;
      float f[8], s = 0.f, q = 0.f;
#pragma unroll
      for (int j = 0; j < 8; j++) { f[j] = bf2f((unsigned short)v[j]); s += f[j]; q += f[j] * f[j]; }
#pragma unroll
      for (int m = 1; m < 64; m <<= 1) { s += __shfl_xor(s, m); q += __shfl_xor(q, m); }
      __syncthreads();
      if ((t & 63) == 0) { sm.red[w] = s; sm.red[4 + w] = q; }
      __syncthreads();
      s = sm.red[0] + sm.red[1] + sm.red[2] + sm.red[3];
      q = sm.red[4] + sm.red[5] + sm.red[6] + sm.red[7];
      float mean = s * (1.f / 2048.f);
      float var = q * (1.f / 2048.f) - mean * mean;
      float inv = rsqrtf(var + 1e-6f);
      const float* sc = part ? ksc : qsc;
      float extra = part ? 1.0f : 0.12751743f;  // (1/sqrt(128))*log2(e)
      s16x8 o;
#pragma unroll
      for (int j = 0; j < 8; j++) o[j] = (short)f2bf((f[j] - mean) * inv * (sc[t * 8 + j] * extra));
      *(s16x8*)p = o;
    }
    return;
  }
  const int b2 = bid - 4096;
  const int bh = b2 >> 5;
  const int b = bh >> 4, h = bh & 15;
  const int s0 = (b2 & 31) * 64;
#pragma unroll
  for (int it = 0; it < 4; ++it) {
    int flat = it * 256 + t;
    int r = flat >> 4, c = flat & 15;
    s16x8 v = *(const s16x8*)(qkv + (size_t)(b * 2048 + s0 + r) * 6144 + 4096 + h * 128 + c * 8);
    *((s16x8*)&sm.tl[r][c * 8]) = v;
  }
  __syncthreads();
#pragma unroll
  for (int it = 0; it < 4; ++it) {
    int flat = it * 256 + t;
    int d = flat >> 3, cs = flat & 7;
    s16x8 o;
#pragma unroll
    for (int e = 0; e < 8; e++) {
      int key = (cs >> 2) * 32 + (e >> 2) * 16 + (cs & 3) * 4 + (e & 3);
      o[e] = (short)sm.tl[key][d];
    }
    *(s16x8*)(vt + (size_t)(bh * 128 + d) * 2048 + s0 + cs * 8) = o;
  }
}

// --------------------------- causal flash attention -------------------------
// QBLK=128 (8 waves x 16 q-rows), KVBLK=64, dbuf LDS 64KB, 512 threads.
// Paired q-tiles: 256 blocks = 1/CU, uniform 34 iterations/block, no tail.
// XCD-grouped flat grid: idx = pair*32 + bh => all 8 pair-blocks of one (b,h)
// land on ONE XCD; its 1MB KV stays L2-resident. (R13 measured best.)
__global__ __launch_bounds__(512) void k_attn(const unsigned short* __restrict__ qkv,
                                              const unsigned short* __restrict__ vt,
                                              unsigned short* __restrict__ ctx) {
  __shared__ unsigned short sK[2][64 * 128];
  __shared__ unsigned short sV[2][128 * 64];
  const int t = threadIdx.x;
  const int w = t >> 6, lane = t & 63, g = lane >> 4, l15 = lane & 15;
  const int idx = (int)blockIdx.x;
  const int pair = idx >> 5;                    // [0,8)
  const int bh = idx & 31;                      // bh fastest -> same XCD per (b,h)
  const int b = bh >> 4, h = bh & 15;
  const int qt0 = 15 - pair, qt1 = pair;        // q-tiles of 128 rows
  const int n0 = 2 * qt0 + 2;                   // KV-iters in segment 0
  const int NT = 34;                            // n0 + 2*qt1+2
  const unsigned short* kbase = qkv + (size_t)(b * 2048) * 6144 + 2048 + h * 128;
  const unsigned short* vbase = vt + (size_t)((b * 16 + h) * 128) * 2048;

  auto issue_kv = [&](int k0, int bufi) {
#pragma unroll
    for (int it2 = 0; it2 < 2; ++it2) {         // K tile 64x128, swz c^(r&15)
      int flat = it2 * 512 + t;
      int r = flat >> 4, c = flat & 15;
      gload_lds16(kbase + (size_t)(k0 + r) * 6144 + ((c ^ (r & 15)) * 8),
                  (unsigned short*)&sK[bufi][flat * 8]);
    }
#pragma unroll
    for (int it2 = 0; it2 < 2; ++it2) {         // V tile 128d x 64, swz z^(d&7)
      int flat = it2 * 512 + t;
      int d = flat >> 3, z = flat & 7;
      gload_lds16(vbase + (size_t)d * 2048 + k0 + ((z ^ (d & 7)) * 8),
                  (unsigned short*)&sV[bufi][flat * 8]);
    }
  };

  s16x8 bq[4];
  auto load_q = [&](int q0) {
#pragma unroll
    for (int ks = 0; ks < 4; ++ks)
      bq[ks] = *(const s16x8*)(qkv + (size_t)(b * 2048 + q0 + w * 16 + l15) * 6144 +
                               h * 128 + (ks * 4 + g) * 8);
  };

  f32x4 o[8];
  float mrun, lrun;
  auto reset_state = [&]() {
#pragma unroll
    for (int nd = 0; nd < 8; ++nd) o[nd] = (f32x4){0.f, 0.f, 0.f, 0.f};
    mrun = -INFINITY; lrun = 0.f;
  };
  auto write_o = [&](int q0) {
    float ivr[4];
#pragma unroll
    for (int r = 0; r < 4; ++r) ivr[r] = 1.0f / __shfl(lrun, 4 * g + r);
#pragma unroll
    for (int nd = 0; nd < 8; ++nd) {
      const int col = h * 128 + nd * 16 + l15;
#pragma unroll
      for (int r = 0; r < 4; ++r) {
        const int row = b * 2048 + q0 + w * 16 + 4 * g + r;
        ctx[(size_t)row * 2048 + col] = f2bf(o[nd][r] * ivr[r]);
      }
    }
  };

  reset_state();
  load_q(qt0 * 128);
  issue_kv(0, 0);
  int cur = 0;

  for (int it = 0; it < NT; ++it) {
    const int seg = (it < n0) ? 0 : 1;
    const int qt = seg ? qt1 : qt0;
    const int kt = seg ? it - n0 : it;          // KV-tile idx within segment

    if (it + 1 < NT) {
      const int kn = (it + 1 < n0) ? it + 1 : it + 1 - n0;
      issue_kv(kn * 64, cur ^ 1);
      asm volatile("s_waitcnt vmcnt(4)" ::: "memory");  // current tile landed
    } else {
      asm volatile("s_waitcnt vmcnt(0)" ::: "memory");
    }
    __builtin_amdgcn_sched_barrier(0);
    __builtin_amdgcn_s_barrier();

    if (seg == 1 && kt == 0) {
      write_o(qt0 * 128);
      reset_state();
      load_q(qt1 * 128);
    }

    const unsigned short* sKc = &sK[cur][0];
    const unsigned short* sVc = &sV[cur][0];

    f32x4 st[4];
#pragma unroll
    for (int mi = 0; mi < 4; ++mi) st[mi] = (f32x4){0.f, 0.f, 0.f, 0.f};
#pragma unroll
    for (int mi = 0; mi < 4; ++mi) {
#pragma unroll
      for (int ks = 0; ks < 4; ++ks) {
        s16x8 ak = *(const s16x8*)&sKc[(mi * 16 + l15) * 128 + (((ks * 4 + g) ^ l15) * 8)];
        st[mi] = __builtin_amdgcn_mfma_f32_16x16x32_bf16(ak, bq[ks], st[mi], 0, 0, 0);
      }
    }

    if (kt >= 2 * qt) {                          // diagonal band: causal mask
      const int qglob = qt * 128 + w * 16 + l15;
#pragma unroll
      for (int mi = 0; mi < 4; ++mi)
#pragma unroll
        for (int r = 0; r < 4; ++r)
          if (kt * 64 + mi * 16 + 4 * g + r > qglob) st[mi][r] = -INFINITY;
    }

    float mt = -INFINITY;
#pragma unroll
    for (int mi = 0; mi < 4; ++mi)
#pragma unroll
      for (int r = 0; r < 4; ++r) mt = fmaxf(mt, st[mi][r]);
    mt = fmaxf(mt, __shfl_xor(mt, 16));
    mt = fmaxf(mt, __shfl_xor(mt, 32));

    if (!__all(mt <= mrun + 8.f)) {              // defer-max: rescale rarely
      const float mnew = fmaxf(mrun, mt);
      const float alpha = exp2f(mrun - mnew);
      lrun *= alpha;
      float ar[4];
#pragma unroll
      for (int r = 0; r < 4; ++r) ar[r] = __shfl(alpha, 4 * g + r);
#pragma unroll
      for (int nd = 0; nd < 8; ++nd)
#pragma unroll
        for (int r = 0; r < 4; ++r) o[nd][r] *= ar[r];
      mrun = mnew;
    }

    float ls = 0.f;
#pragma unroll
    for (int mi = 0; mi < 4; ++mi)
#pragma unroll
      for (int r = 0; r < 4; ++r) {
        float pp = exp2f(st[mi][r] - mrun);
        st[mi][r] = pp;
        ls += pp;
      }
    ls += __shfl_xor(ls, 16);
    ls += __shfl_xor(ls, 32);
    lrun += ls;

    s16x8 pa01, pa23;  // P as PV A-operand: slot j <-> key (j>>2)*16+4g+(j&3)
#pragma unroll
    for (int j = 0; j < 8; ++j) {
      pa01[j] = (short)f2bf(st[j >> 2][j & 3]);
      pa23[j] = (short)f2bf(st[2 + (j >> 2)][j & 3]);
    }

#pragma unroll
    for (int nd = 0; nd < 8; ++nd) {
      const int d = nd * 16 + l15;
      const int zs = d & 7;
      s16x8 bv0 = *(const s16x8*)&sVc[d * 64 + ((g ^ zs) * 8)];
      s16x8 bv1 = *(const s16x8*)&sVc[d * 64 + (((4 + g) ^ zs) * 8)];
      o[nd] = __builtin_amdgcn_mfma_f32_16x16x32_bf16(pa01, bv0, o[nd], 0, 0, 0);
      o[nd] = __builtin_amdgcn_mfma_f32_16x16x32_bf16(pa23, bv1, o[nd], 0, 0, 0);
    }

    __builtin_amdgcn_sched_barrier(0);
    __builtin_amdgcn_s_barrier();                // reads of buf[cur] done
    cur ^= 1;
  }
  write_o(qt1 * 128);
}

// ---------------------------------------------------------------------------
extern "C" void kernel_launch(void* const* d_in, const int* in_sizes, int n_in,
                              void* d_out, int out_size, void* d_ws, size_t ws_size,
                              hipStream_t stream) {
  (void)in_sizes; (void)n_in; (void)out_size; (void)ws_size;
  const float* x    = (const float*)d_in[0];
  const float* Wqkv = (const float*)d_in[1];
  const float* qsc  = (const float*)d_in[2];
  const float* ksc  = (const float*)d_in[3];
  const float* outW = (const float*)d_in[4];

  char* ws = (char*)d_ws;
  unsigned short* xb  = (unsigned short*)(ws);              // 16.8MB (reused as ctx)
  unsigned short* wT  = (unsigned short*)(ws + 16777216);   // 25.2MB  Wqkv^T bf16
  unsigned short* owT = (unsigned short*)(ws + 41943040);   // 8.4MB   out_W^T bf16
  unsigned short* qkv = (unsigned short*)(ws + 50331648);   // 50.3MB  qkv bf16 (LN in place)
  unsigned short* vt  = (unsigned short*)(ws + 100663296);  // 16.8MB  v^T per head
  unsigned short* ctx = xb;                                 // x dead after QKV GEMM

  // preproc: cvt (8192) + Wqkv^T (12288) + outW^T (4096)
  k_pre<<<24576, 256, 0, stream>>>((const float4*)x, (s16x4*)xb, Wqkv, wT, outW, owT);
  // QKV: 32 m x 24 n = 768 blocks = exactly 3 blocks/CU co-resident
  k_gw<1, 8, 3><<<768, 256, 0, stream>>>(xb, wT, qkv, 6144, 2048, 3);
  // LN (4096) + V-transpose (1024)
  k_lnvt<<<5120, 256, 0, stream>>>(qkv, qsc, ksc, vt);
  // attn: 256 blocks flat, idx = pair*32 + bh (XCD-grouped KV reuse)
  k_attn<<<256, 512, 0, stream>>>(qkv, vt, ctx);
  // out-proj: 32 m x 32 n = 1024 blocks, 48KB LDS -> 3 blocks/CU co-resident
  k_go3<<<1024, 256, 0, stream>>>(ctx, owT, (float*)d_out, 2048, 2048, 4);
}

// Round 15
// 254.825 us; speedup vs baseline: 1.0688x; 1.0688x over previous
//
#include <hip/hip_runtime.h>

// ---------------------------------------------------------------------------
// FlaxAttention: x@Wqkv -> LN(q),LN(k) -> causal flash attn -> ctx@out_W
// B=2 S=2048 D=2048 H=16 Dh=128. All matmuls bf16 MFMA (fp32 accum).
// ---------------------------------------------------------------------------

typedef float f32x4 __attribute__((ext_vector_type(4)));
typedef short s16x8 __attribute__((ext_vector_type(8)));
typedef short s16x4 __attribute__((ext_vector_type(4)));

static __device__ __forceinline__ unsigned short f2bf(float f) {
  unsigned u = __builtin_bit_cast(unsigned, f);
  unsigned r = u + 0x7fffu + ((u >> 16) & 1u);   // RNE
  return (unsigned short)(r >> 16);
}
static __device__ __forceinline__ float bf2f(unsigned short s) {
  unsigned u = ((unsigned)s) << 16;
  return __builtin_bit_cast(float, u);
}

static __device__ __forceinline__ void gload_lds16(const unsigned short* g, unsigned short* l) {
  __builtin_amdgcn_global_load_lds((const __attribute__((address_space(1))) void*)g,
                                   (__attribute__((address_space(3))) void*)l, 16, 0, 0);
}

// -------- fused preprocessing: x->bf16, Wqkv^T->bf16, outW^T->bf16 ----------
// blocks [0,8192): cvt x (float4/thread)
// blocks [8192,11264): Wqkv [2048][6144] -> wT [6144][2048], 64x64 tiles
// blocks [11264,12288): outW [2048][2048] -> owT, 64x64 tiles
// 64x64 tiles: fp32 reads 256B/row, bf16 writes 128B/row (vs 64B at 32x32).
__global__ __launch_bounds__(256) void k_pre(const float4* __restrict__ x,
                                             s16x4* __restrict__ xb,
                                             const float* __restrict__ Wqkv,
                                             unsigned short* __restrict__ wT,
                                             const float* __restrict__ outW,
                                             unsigned short* __restrict__ owT) {
  __shared__ float tile[64][65];
  const int bid = blockIdx.x, t = threadIdx.x;
  if (bid < 8192) {
    int i = bid * 256 + t;
    float4 v = x[i];
    s16x4 o = { (short)f2bf(v.x), (short)f2bf(v.y), (short)f2bf(v.z), (short)f2bf(v.w) };
    xb[i] = o;
    return;
  }
  const float* in;
  unsigned short* out;
  int K = 2048, N, n0, k0;
  if (bid < 11264) {
    int b2 = bid - 8192;                 // 32 x 96 tiles
    in = Wqkv; out = wT; N = 6144;
    k0 = (b2 / 96) * 64; n0 = (b2 % 96) * 64;
  } else {
    int b2 = bid - 11264;                // 32 x 32 tiles
    in = outW; out = owT; N = 2048;
    k0 = (b2 >> 5) * 64; n0 = (b2 & 31) * 64;
  }
  const int tx = t & 63, ty = t >> 6;
#pragma unroll
  for (int rr = 0; rr < 16; ++rr) {
    int kr = ty + rr * 4;
    tile[kr][tx] = in[(size_t)(k0 + kr) * N + n0 + tx];
  }
  __syncthreads();
#pragma unroll
  for (int rr = 0; rr < 16; ++rr) {
    int nr = ty + rr * 4;
    out[(size_t)(n0 + nr) * K + k0 + tx] = f2bf(tile[tx][nr]);
  }
}

// ---- 128 x (NFN*32) GEMM, BK=32, dbuf, 4 waves, 3 blocks/CU (bf16 MFMA) ----
// (unchanged from R6 -- measured best: ~111us/936TF on QKV, MfmaUtil 40%)
template <int BF16OUT, int NFN, int MINW>
__global__ __launch_bounds__(256, MINW) void k_gw(const unsigned short* __restrict__ A,
                                                  const unsigned short* __restrict__ Bt,
                                                  void* __restrict__ Cout,
                                                  int N, int K, int npx) {
  __shared__ unsigned short sA[2 * 128 * 32];            // 16KB
  __shared__ unsigned short sB[2 * NFN * 32 * 32];       // 32KB @NFN=8
  const int t = threadIdx.x;
  const int wid = t >> 6, lane = t & 63, g = lane >> 4, l15 = lane & 15;
  const int wm = wid >> 1, wn = wid & 1;

  const int xcd = (int)blockIdx.x & 7, idx = (int)blockIdx.x >> 3;
  const int m0 = (idx / npx) * 128;
  const int n0 = (xcd * npx + idx % npx) * (NFN * 32);

  const int u = (t & 7) ^ ((t >> 3) & 7);
  const int srow = 2 * (t >> 3) + (u >> 2);
  const int sk = (u & 3) * 8;
  const unsigned short* pA = A  + (size_t)(m0 + srow) * K + sk;
  const unsigned short* pB = Bt + (size_t)(n0 + srow) * K + sk;

  auto stage = [&](int kt, int buf) {
#pragma unroll
    for (int j = 0; j < 2; ++j)
      gload_lds16(pA + (size_t)(j * 64) * K + kt * 32,
                  sA + buf * 4096 + j * 2048 + t * 8);
#pragma unroll
    for (int j = 0; j < NFN / 2; ++j)
      gload_lds16(pB + (size_t)(j * 64) * K + kt * 32,
                  sB + buf * (NFN * 1024) + j * 2048 + t * 8);
  };

  const int si = (((l15 & 1) * 4 + g) ^ ((l15 >> 1) & 7));
  const int baseA = (wm * 32 + (l15 >> 1)) * 64 + si * 8;
  const int baseB = (wn * NFN * 8 + (l15 >> 1)) * 64 + si * 8;

  f32x4 acc[4][NFN];
#pragma unroll
  for (int fm = 0; fm < 4; ++fm)
#pragma unroll
    for (int fn = 0; fn < NFN; ++fn) acc[fm][fn] = (f32x4){0.f, 0.f, 0.f, 0.f};

  const int NK = K >> 5;
  stage(0, 0); stage(1, 1);
  if constexpr (NFN == 8) asm volatile("s_waitcnt vmcnt(6)" ::: "memory");
  else                    asm volatile("s_waitcnt vmcnt(4)" ::: "memory");
  __builtin_amdgcn_sched_barrier(0);
  __builtin_amdgcn_s_barrier();

  for (int s = 0; s < NK; ++s) {
    const unsigned short* aT = sA + (s & 1) * 4096;
    const unsigned short* bT = sB + (s & 1) * (NFN * 1024);

    s16x8 af[4];
#pragma unroll
    for (int fm = 0; fm < 4; ++fm) af[fm] = *(const s16x8*)&aT[baseA + fm * 512];
    __builtin_amdgcn_s_setprio(1);
#pragma unroll
    for (int fn = 0; fn < NFN; ++fn) {
      s16x8 bf = *(const s16x8*)&bT[baseB + fn * 512];
#pragma unroll
      for (int fm = 0; fm < 4; ++fm)
        acc[fm][fn] = __builtin_amdgcn_mfma_f32_16x16x32_bf16(af[fm], bf, acc[fm][fn], 0, 0, 0);
    }
    __builtin_amdgcn_s_setprio(0);

    __builtin_amdgcn_sched_barrier(0);
    __builtin_amdgcn_s_barrier();            // all reads of buf[s&1] complete
    if (s + 2 < NK) {
      stage(s + 2, s & 1);                   // refill the buffer just freed
      if constexpr (NFN == 8) asm volatile("s_waitcnt vmcnt(6)" ::: "memory");
      else                    asm volatile("s_waitcnt vmcnt(4)" ::: "memory");
    } else if (s + 1 < NK) {
      asm volatile("s_waitcnt vmcnt(0)" ::: "memory");
    }
    __builtin_amdgcn_sched_barrier(0);
    __builtin_amdgcn_s_barrier();            // tile s+1 visible to all
  }

#pragma unroll
  for (int fm = 0; fm < 4; ++fm)
#pragma unroll
    for (int fn = 0; fn < NFN; ++fn)
#pragma unroll
      for (int r = 0; r < 4; ++r) {
        const int row = m0 + wm * 64 + fm * 16 + g * 4 + r;
        const int col = n0 + wn * (NFN * 16) + fn * 16 + l15;
        if (BF16OUT)
          ((unsigned short*)Cout)[(size_t)row * N + col] = f2bf(acc[fm][fn][r]);
        else
          ((float*)Cout)[(size_t)row * N + col] = acc[fm][fn][r];
      }
}

// ------- out-projection GEMM: 128x128 tile, BK=64, dbuf, 2 blocks/CU --------
// (R11/R13 measured config -- out-proj converged here; R12/R14 variants lost)
__global__ __launch_bounds__(256, 2) void k_go(const unsigned short* __restrict__ A,
                                               const unsigned short* __restrict__ Bt,
                                               float* __restrict__ Cout,
                                               int N, int K, int npx) {
  __shared__ unsigned short sA[2 * 128 * 64];   // 32KB
  __shared__ unsigned short sB[2 * 128 * 64];   // 32KB
  const int t = threadIdx.x;
  const int wid = t >> 6, lane = t & 63, g = lane >> 4, l15 = lane & 15;
  const int wm = wid >> 1, wn = wid & 1;

  const int xcd = (int)blockIdx.x & 7, idx = (int)blockIdx.x >> 3;
  const int m0 = (idx / npx) * 128;
  const int n0 = (xcd * npx + idx % npx) * 128;

  const int u = (t & 7) ^ ((t >> 3) & 7);
  const unsigned short* pA = A  + (size_t)(m0 + (t >> 3)) * K + u * 8;
  const unsigned short* pB = Bt + (size_t)(n0 + (t >> 3)) * K + u * 8;

  auto stage = [&](int kt, int buf) {
#pragma unroll
    for (int j = 0; j < 4; ++j)
      gload_lds16(pA + (size_t)(j * 32) * K + kt * 64,
                  sA + buf * 8192 + j * 2048 + t * 8);
#pragma unroll
    for (int j = 0; j < 4; ++j)
      gload_lds16(pB + (size_t)(j * 32) * K + kt * 64,
                  sB + buf * 8192 + j * 2048 + t * 8);
  };

  const int x7 = l15 & 7;
  const int sl0 = (g ^ x7) * 8, sl1 = ((4 + g) ^ x7) * 8;
  const int baseA = (wm * 64 + l15) * 64;
  const int baseB = (wn * 64 + l15) * 64;

  f32x4 acc[4][4];
#pragma unroll
  for (int fm = 0; fm < 4; ++fm)
#pragma unroll
    for (int fn = 0; fn < 4; ++fn) acc[fm][fn] = (f32x4){0.f, 0.f, 0.f, 0.f};

  const int NK = K >> 6;
  stage(0, 0); stage(1, 1);
  asm volatile("s_waitcnt vmcnt(8)" ::: "memory");
  __builtin_amdgcn_sched_barrier(0);
  __builtin_amdgcn_s_barrier();

  for (int s = 0; s < NK; ++s) {
    const unsigned short* aT = sA + (s & 1) * 8192;
    const unsigned short* bT = sB + (s & 1) * 8192;

    s16x8 af[4][2];
#pragma unroll
    for (int fm = 0; fm < 4; ++fm) {
      af[fm][0] = *(const s16x8*)&aT[baseA + fm * 1024 + sl0];
      af[fm][1] = *(const s16x8*)&aT[baseA + fm * 1024 + sl1];
    }
    __builtin_amdgcn_s_setprio(1);
#pragma unroll
    for (int fn = 0; fn < 4; ++fn) {
      s16x8 bf0 = *(const s16x8*)&bT[baseB + fn * 1024 + sl0];
      s16x8 bf1 = *(const s16x8*)&bT[baseB + fn * 1024 + sl1];
#pragma unroll
      for (int fm = 0; fm < 4; ++fm) {
        acc[fm][fn] = __builtin_amdgcn_mfma_f32_16x16x32_bf16(af[fm][0], bf0, acc[fm][fn], 0, 0, 0);
        acc[fm][fn] = __builtin_amdgcn_mfma_f32_16x16x32_bf16(af[fm][1], bf1, acc[fm][fn], 0, 0, 0);
      }
    }
    __builtin_amdgcn_s_setprio(0);

    __builtin_amdgcn_sched_barrier(0);
    __builtin_amdgcn_s_barrier();
    if (s + 2 < NK) {
      stage(s + 2, s & 1);
      asm volatile("s_waitcnt vmcnt(8)" ::: "memory");
    } else if (s + 1 < NK) {
      asm volatile("s_waitcnt vmcnt(0)" ::: "memory");
    }
    __builtin_amdgcn_sched_barrier(0);
    __builtin_amdgcn_s_barrier();
  }

#pragma unroll
  for (int fm = 0; fm < 4; ++fm)
#pragma unroll
    for (int fn = 0; fn < 4; ++fn)
#pragma unroll
      for (int r = 0; r < 4; ++r) {
        const int row = m0 + wm * 64 + fm * 16 + g * 4 + r;
        const int col = n0 + wn * 64 + fn * 16 + l15;
        Cout[(size_t)row * N + col] = acc[fm][fn][r];
      }
}

// ------- fused: LayerNorm(q,k) in place + V -> v_t PV-fragment order --------
__global__ __launch_bounds__(256) void k_lnvt(unsigned short* __restrict__ qkv,
                                              const float* __restrict__ qsc,
                                              const float* __restrict__ ksc,
                                              unsigned short* __restrict__ vt) {
  __shared__ union {
    float red[8];
    unsigned short tl[64][136];
  } sm;
  const int bid = blockIdx.x, t = threadIdx.x;
  if (bid < 4096) {
    const int w = t >> 6;
    unsigned short* base = qkv + (size_t)bid * 6144;
#pragma unroll
    for (int part = 0; part < 2; ++part) {
      unsigned short* p = base + part * 2048 + t * 8;
      s16x8 v = *(const s16x8*)p;
      float f[8], s = 0.f, q = 0.f;
#pragma unroll
      for (int j = 0; j < 8; j++) { f[j] = bf2f((unsigned short)v[j]); s += f[j]; q += f[j] * f[j]; }
#pragma unroll
      for (int m = 1; m < 64; m <<= 1) { s += __shfl_xor(s, m); q += __shfl_xor(q, m); }
      __syncthreads();
      if ((t & 63) == 0) { sm.red[w] = s; sm.red[4 + w] = q; }
      __syncthreads();
      s = sm.red[0] + sm.red[1] + sm.red[2] + sm.red[3];
      q = sm.red[4] + sm.red[5] + sm.red[6] + sm.red[7];
      float mean = s * (1.f / 2048.f);
      float var = q * (1.f / 2048.f) - mean * mean;
      float inv = rsqrtf(var + 1e-6f);
      const float* sc = part ? ksc : qsc;
      float extra = part ? 1.0f : 0.12751743f;  // (1/sqrt(128))*log2(e)
      s16x8 o;
#pragma unroll
      for (int j = 0; j < 8; j++) o[j] = (short)f2bf((f[j] - mean) * inv * (sc[t * 8 + j] * extra));
      *(s16x8*)p = o;
    }
    return;
  }
  const int b2 = bid - 4096;
  const int bh = b2 >> 5;
  const int b = bh >> 4, h = bh & 15;
  const int s0 = (b2 & 31) * 64;
#pragma unroll
  for (int it = 0; it < 4; ++it) {
    int flat = it * 256 + t;
    int r = flat >> 4, c = flat & 15;
    s16x8 v = *(const s16x8*)(qkv + (size_t)(b * 2048 + s0 + r) * 6144 + 4096 + h * 128 + c * 8);
    *((s16x8*)&sm.tl[r][c * 8]) = v;
  }
  __syncthreads();
#pragma unroll
  for (int it = 0; it < 4; ++it) {
    int flat = it * 256 + t;
    int d = flat >> 3, cs = flat & 7;
    s16x8 o;
#pragma unroll
    for (int e = 0; e < 8; e++) {
      int key = (cs >> 2) * 32 + (e >> 2) * 16 + (cs & 3) * 4 + (e & 3);
      o[e] = (short)sm.tl[key][d];
    }
    *(s16x8*)(vt + (size_t)(bh * 128 + d) * 2048 + s0 + cs * 8) = o;
  }
}

// --------------------------- causal flash attention -------------------------
// QBLK=128 (8 waves x 16 q-rows), KVBLK=64, dbuf LDS 64KB, 512 threads.
// Paired q-tiles: 256 blocks = 1/CU, uniform 34 iterations/block, no tail.
// XCD-grouped flat grid: idx = pair*32 + bh => all 8 pair-blocks of one (b,h)
// land on ONE XCD; its 1MB KV stays L2-resident. (R13 measured best.)
__global__ __launch_bounds__(512) void k_attn(const unsigned short* __restrict__ qkv,
                                              const unsigned short* __restrict__ vt,
                                              unsigned short* __restrict__ ctx) {
  __shared__ unsigned short sK[2][64 * 128];
  __shared__ unsigned short sV[2][128 * 64];
  const int t = threadIdx.x;
  const int w = t >> 6, lane = t & 63, g = lane >> 4, l15 = lane & 15;
  const int idx = (int)blockIdx.x;
  const int pair = idx >> 5;                    // [0,8)
  const int bh = idx & 31;                      // bh fastest -> same XCD per (b,h)
  const int b = bh >> 4, h = bh & 15;
  const int qt0 = 15 - pair, qt1 = pair;        // q-tiles of 128 rows
  const int n0 = 2 * qt0 + 2;                   // KV-iters in segment 0
  const int NT = 34;                            // n0 + 2*qt1+2
  const unsigned short* kbase = qkv + (size_t)(b * 2048) * 6144 + 2048 + h * 128;
  const unsigned short* vbase = vt + (size_t)((b * 16 + h) * 128) * 2048;

  auto issue_kv = [&](int k0, int bufi) {
#pragma unroll
    for (int it2 = 0; it2 < 2; ++it2) {         // K tile 64x128, swz c^(r&15)
      int flat = it2 * 512 + t;
      int r = flat >> 4, c = flat & 15;
      gload_lds16(kbase + (size_t)(k0 + r) * 6144 + ((c ^ (r & 15)) * 8),
                  (unsigned short*)&sK[bufi][flat * 8]);
    }
#pragma unroll
    for (int it2 = 0; it2 < 2; ++it2) {         // V tile 128d x 64, swz z^(d&7)
      int flat = it2 * 512 + t;
      int d = flat >> 3, z = flat & 7;
      gload_lds16(vbase + (size_t)d * 2048 + k0 + ((z ^ (d & 7)) * 8),
                  (unsigned short*)&sV[bufi][flat * 8]);
    }
  };

  s16x8 bq[4];
  auto load_q = [&](int q0) {
#pragma unroll
    for (int ks = 0; ks < 4; ++ks)
      bq[ks] = *(const s16x8*)(qkv + (size_t)(b * 2048 + q0 + w * 16 + l15) * 6144 +
                               h * 128 + (ks * 4 + g) * 8);
  };

  f32x4 o[8];
  float mrun, lrun;
  auto reset_state = [&]() {
#pragma unroll
    for (int nd = 0; nd < 8; ++nd) o[nd] = (f32x4){0.f, 0.f, 0.f, 0.f};
    mrun = -INFINITY; lrun = 0.f;
  };
  auto write_o = [&](int q0) {
    float ivr[4];
#pragma unroll
    for (int r = 0; r < 4; ++r) ivr[r] = 1.0f / __shfl(lrun, 4 * g + r);
#pragma unroll
    for (int nd = 0; nd < 8; ++nd) {
      const int col = h * 128 + nd * 16 + l15;
#pragma unroll
      for (int r = 0; r < 4; ++r) {
        const int row = b * 2048 + q0 + w * 16 + 4 * g + r;
        ctx[(size_t)row * 2048 + col] = f2bf(o[nd][r] * ivr[r]);
      }
    }
  };

  reset_state();
  load_q(qt0 * 128);
  issue_kv(0, 0);
  int cur = 0;

  for (int it = 0; it < NT; ++it) {
    const int seg = (it < n0) ? 0 : 1;
    const int qt = seg ? qt1 : qt0;
    const int kt = seg ? it - n0 : it;          // KV-tile idx within segment

    if (it + 1 < NT) {
      const int kn = (it + 1 < n0) ? it + 1 : it + 1 - n0;
      issue_kv(kn * 64, cur ^ 1);
      asm volatile("s_waitcnt vmcnt(4)" ::: "memory");  // current tile landed
    } else {
      asm volatile("s_waitcnt vmcnt(0)" ::: "memory");
    }
    __builtin_amdgcn_sched_barrier(0);
    __builtin_amdgcn_s_barrier();

    if (seg == 1 && kt == 0) {
      write_o(qt0 * 128);
      reset_state();
      load_q(qt1 * 128);
    }

    const unsigned short* sKc = &sK[cur][0];
    const unsigned short* sVc = &sV[cur][0];

    f32x4 st[4];
#pragma unroll
    for (int mi = 0; mi < 4; ++mi) st[mi] = (f32x4){0.f, 0.f, 0.f, 0.f};
#pragma unroll
    for (int mi = 0; mi < 4; ++mi) {
#pragma unroll
      for (int ks = 0; ks < 4; ++ks) {
        s16x8 ak = *(const s16x8*)&sKc[(mi * 16 + l15) * 128 + (((ks * 4 + g) ^ l15) * 8)];
        st[mi] = __builtin_amdgcn_mfma_f32_16x16x32_bf16(ak, bq[ks], st[mi], 0, 0, 0);
      }
    }

    if (kt >= 2 * qt) {                          // diagonal band: causal mask
      const int qglob = qt * 128 + w * 16 + l15;
#pragma unroll
      for (int mi = 0; mi < 4; ++mi)
#pragma unroll
        for (int r = 0; r < 4; ++r)
          if (kt * 64 + mi * 16 + 4 * g + r > qglob) st[mi][r] = -INFINITY;
    }

    float mt = -INFINITY;
#pragma unroll
    for (int mi = 0; mi < 4; ++mi)
#pragma unroll
      for (int r = 0; r < 4; ++r) mt = fmaxf(mt, st[mi][r]);
    mt = fmaxf(mt, __shfl_xor(mt, 16));
    mt = fmaxf(mt, __shfl_xor(mt, 32));

    if (!__all(mt <= mrun + 8.f)) {              // defer-max: rescale rarely
      const float mnew = fmaxf(mrun, mt);
      const float alpha = exp2f(mrun - mnew);
      lrun *= alpha;
      float ar[4];
#pragma unroll
      for (int r = 0; r < 4; ++r) ar[r] = __shfl(alpha, 4 * g + r);
#pragma unroll
      for (int nd = 0; nd < 8; ++nd)
#pragma unroll
        for (int r = 0; r < 4; ++r) o[nd][r] *= ar[r];
      mrun = mnew;
    }

    float ls = 0.f;
#pragma unroll
    for (int mi = 0; mi < 4; ++mi)
#pragma unroll
      for (int r = 0; r < 4; ++r) {
        float pp = exp2f(st[mi][r] - mrun);
        st[mi][r] = pp;
        ls += pp;
      }
    ls += __shfl_xor(ls, 16);
    ls += __shfl_xor(ls, 32);
    lrun += ls;

    s16x8 pa01, pa23;  // P as PV A-operand: slot j <-> key (j>>2)*16+4g+(j&3)
#pragma unroll
    for (int j = 0; j < 8; ++j) {
      pa01[j] = (short)f2bf(st[j >> 2][j & 3]);
      pa23[j] = (short)f2bf(st[2 + (j >> 2)][j & 3]);
    }

#pragma unroll
    for (int nd = 0; nd < 8; ++nd) {
      const int d = nd * 16 + l15;
      const int zs = d & 7;
      s16x8 bv0 = *(const s16x8*)&sVc[d * 64 + ((g ^ zs) * 8)];
      s16x8 bv1 = *(const s16x8*)&sVc[d * 64 + (((4 + g) ^ zs) * 8)];
      o[nd] = __builtin_amdgcn_mfma_f32_16x16x32_bf16(pa01, bv0, o[nd], 0, 0, 0);
      o[nd] = __builtin_amdgcn_mfma_f32_16x16x32_bf16(pa23, bv1, o[nd], 0, 0, 0);
    }

    __builtin_amdgcn_sched_barrier(0);
    __builtin_amdgcn_s_barrier();                // reads of buf[cur] done
    cur ^= 1;
  }
  write_o(qt1 * 128);
}

// ---------------------------------------------------------------------------
extern "C" void kernel_launch(void* const* d_in, const int* in_sizes, int n_in,
                              void* d_out, int out_size, void* d_ws, size_t ws_size,
                              hipStream_t stream) {
  (void)in_sizes; (void)n_in; (void)out_size; (void)ws_size;
  const float* x    = (const float*)d_in[0];
  const float* Wqkv = (const float*)d_in[1];
  const float* qsc  = (const float*)d_in[2];
  const float* ksc  = (const float*)d_in[3];
  const float* outW = (const float*)d_in[4];

  char* ws = (char*)d_ws;
  unsigned short* xb  = (unsigned short*)(ws);              // 16.8MB (reused as ctx)
  unsigned short* wT  = (unsigned short*)(ws + 16777216);   // 25.2MB  Wqkv^T bf16
  unsigned short* owT = (unsigned short*)(ws + 41943040);   // 8.4MB   out_W^T bf16
  unsigned short* qkv = (unsigned short*)(ws + 50331648);   // 50.3MB  qkv bf16 (LN in place)
  unsigned short* vt  = (unsigned short*)(ws + 100663296);  // 16.8MB  v^T per head
  unsigned short* ctx = xb;                                 // x dead after QKV GEMM

  // preproc: cvt (8192) + Wqkv^T (3072) + outW^T (1024), 64x64 tiles
  k_pre<<<12288, 256, 0, stream>>>((const float4*)x, (s16x4*)xb, Wqkv, wT, outW, owT);
  // QKV: 32 m x 24 n = 768 blocks = exactly 3 blocks/CU co-resident
  k_gw<1, 8, 3><<<768, 256, 0, stream>>>(xb, wT, qkv, 6144, 2048, 3);
  // LN (4096) + V-transpose (1024)
  k_lnvt<<<5120, 256, 0, stream>>>(qkv, qsc, ksc, vt);
  // attn: 256 blocks flat, idx = pair*32 + bh (XCD-grouped KV reuse)
  k_attn<<<256, 512, 0, stream>>>(qkv, vt, ctx);
  // out-proj: 32 m x 16 n = 512 blocks = 2 blocks/CU, BK=64
  k_go<<<512, 256, 0, stream>>>(ctx, owT, (float*)d_out, 2048, 2048, 2);
}